// Round 7
// baseline (450.087 us; speedup 1.0000x reference)
//
#include <hip/hip_runtime.h>
#include <math.h>

#define Wd 256
#define Hd 256
#define Nd (Wd*Hd)
#define Bd 8

// wtab layout: [i][o][12]: k=0..8 conv taps (center has +identity), k=9 Wmp[o][i],
// k=10,11 pad. bias[12] (= bh+bmp) at offset 1728. Lives in spare d_out space.
__global__ __launch_bounds__(256) void nca_prep(
    const float* __restrict__ Wh, const float* __restrict__ bh,
    const float* __restrict__ Wmp, const float* __restrict__ bmp,
    float* __restrict__ wtab)
{
    int idx = blockIdx.x * 256 + threadIdx.x;
    if (idx < 1728) {
        int i = idx / 144, rem = idx % 144, o = rem / 12, k = rem % 12;
        float v = 0.0f;
        if (k < 9) {
            v = Wh[(o * 12 + i) * 9 + k];
            if (k == 4 && o == i) v += 1.0f;
        } else if (k == 9) {
            v = Wmp[o * 12 + i];
        }
        wtab[idx] = v;
    } else if (idx < 1740) {
        int o = idx - 1728;
        wtab[idx] = bh[o] + bmp[o];
    }
}

// One NCA step. Taps AND weights from LDS (both on in-order lgkmcnt; no SMEM,
// no global loads in the compute loop). Weights read as ds_read_b128 broadcasts.
// 32x32 tile, 256 threads, 4 px/thread. Borders pre-zeroed in LDS -> no masks.
__global__ __launch_bounds__(256, 2) void nca_step(
    const float* __restrict__ src, int sbs, int soff,
    float* __restrict__ dst, const float* __restrict__ wtab)
{
    __shared__ float tile[12 * 34 * 36];  // [c][lrow 0..33][stride 36]; lrow0=gy0-1, lcol0=gx0-1
    __shared__ float wlds[1740];

    const int tid = threadIdx.x;
    const int bx = blockIdx.x, by = blockIdx.y, b = blockIdx.z;
    const int x0 = bx * 32, y0 = by * 32;
    const float* sp = src + b * sbs + soff;

    // ---- stage weights (coalesced copy) ----
    for (int idx = tid; idx < 1740; idx += 256) wlds[idx] = wtab[idx];

    // ---- stage 34x34x12 halo tile; 5 slots/thread, divmod once, reused over c ----
    int jr[5], jc[5]; bool jv[5];
    #pragma unroll
    for (int k = 0; k < 5; ++k) {
        int j = tid + k * 256;
        jv[k] = j < 1156;                 // 34*34
        jr[k] = j / 34; jc[k] = j % 34;
    }
    #pragma unroll 1
    for (int c = 0; c < 12; ++c) {
        const float* cp = sp + c * Nd;
        #pragma unroll
        for (int k = 0; k < 5; ++k) {
            if (jv[k]) {
                int gy = y0 + jr[k] - 1, gx = x0 + jc[k] - 1;
                float v = 0.0f;
                if ((unsigned)gy < 256u && (unsigned)gx < 256u) v = cp[gy * Wd + gx];
                tile[c * 1224 + jr[k] * 36 + jc[k]] = v;
            }
        }
    }
    __syncthreads();

    // ---- compute: 4 px along x per thread ----
    const int tx = tid & 7, ty = tid >> 3;       // ty 0..31
    const int px0 = tx * 4;
    const int gx0 = x0 + px0, gy = y0 + ty;

    float dinv[4];
    #pragma unroll
    for (int p = 0; p < 4; ++p) {
        int gx = gx0 + p;
        int deg = (gx > 0) + (gx < Wd - 1) + (gy > 0) + (gy < Hd - 1);
        dinv[p] = 1.0f / (float)deg;
    }

    float acc[4][12];
    #pragma unroll
    for (int o = 0; o < 12; ++o) {
        float bv = wlds[1728 + o];               // same-addr ds_read -> broadcast
        #pragma unroll
        for (int p = 0; p < 4; ++p) acc[p][o] = bv;
    }

    #pragma unroll 1
    for (int i = 0; i < 12; ++i) {
        // taps: per row one aligned b128 (lcols tx*4..+3) + one b64 (lcols tx*4+4,+5)
        const int base = i * 1224 + ty * 36 + px0;   // lrow ty = image row gy-1
        float e0[6], e1[6], e2[6];
        {
            float4 A0 = *(const float4*)&tile[base];
            float2 B0 = *(const float2*)&tile[base + 4];
            float4 A1 = *(const float4*)&tile[base + 36];
            float2 B1 = *(const float2*)&tile[base + 40];
            float4 A2 = *(const float4*)&tile[base + 72];
            float2 B2 = *(const float2*)&tile[base + 76];
            e0[0]=A0.x; e0[1]=A0.y; e0[2]=A0.z; e0[3]=A0.w; e0[4]=B0.x; e0[5]=B0.y;
            e1[0]=A1.x; e1[1]=A1.y; e1[2]=A1.z; e1[3]=A1.w; e1[4]=B1.x; e1[5]=B1.y;
            e2[0]=A2.x; e2[1]=A2.y; e2[2]=A2.z; e2[3]=A2.w; e2[4]=B2.x; e2[5]=B2.y;
        }
        float ns[4];
        #pragma unroll
        for (int p = 0; p < 4; ++p)
            ns[p] = (e0[p + 1] + e2[p + 1] + e1[p] + e1[p + 2]) * dinv[p];

        const int wb = i * 144;
        #pragma unroll
        for (int o = 0; o < 12; ++o) {
            // 10 weights as 3 x ds_read_b128 broadcast (same addr across lanes)
            float4 wa = *(const float4*)&wlds[wb + o * 12];
            float4 wbv = *(const float4*)&wlds[wb + o * 12 + 4];
            float4 wc = *(const float4*)&wlds[wb + o * 12 + 8];
            #pragma unroll
            for (int p = 0; p < 4; ++p) {
                float a = acc[p][o];
                a = fmaf(wa.x, e0[p],     a);
                a = fmaf(wa.y, e0[p + 1], a);
                a = fmaf(wa.z, e0[p + 2], a);
                a = fmaf(wa.w, e1[p],     a);
                a = fmaf(wbv.x, e1[p + 1], a);
                a = fmaf(wbv.y, e1[p + 2], a);
                a = fmaf(wbv.z, e2[p],     a);
                a = fmaf(wbv.w, e2[p + 1], a);
                a = fmaf(wc.x,  e2[p + 2], a);
                a = fmaf(wc.y,  ns[p],     a);
                acc[p][o] = a;
            }
        }
    }

    // ---- elu + float4 store ----
    float* dp = dst + (long)b * (12L * Nd) + (long)gy * Wd + gx0;
    #pragma unroll
    for (int o = 0; o < 12; ++o) {
        float e[4];
        #pragma unroll
        for (int p = 0; p < 4; ++p) {
            float a = acc[p][o];
            e[p] = a > 0.0f ? a : (__expf(a) - 1.0f);
        }
        *(float4*)&dp[(long)o * Nd] = make_float4(e[0], e[1], e[2], e[3]);
    }
}

// Final: alive/rgb heads + pack output (B,16,H,W)
__global__ __launch_bounds__(256) void nca_final(
    const float* __restrict__ hsrc, float* __restrict__ out,
    const float* __restrict__ Wa, const float* __restrict__ ba,
    const float* __restrict__ Wr1, const float* __restrict__ br1,
    const float* __restrict__ Wr2, const float* __restrict__ br2)
{
    int p = blockIdx.x * 256 + threadIdx.x;
    int b = blockIdx.y;
    const float* hp = hsrc + (long)b * 12 * Nd + p;
    float h[12];
    #pragma unroll
    for (int c = 0; c < 12; ++c) h[c] = hp[(long)c * Nd];

    float za = ba[0];
    #pragma unroll
    for (int c = 0; c < 12; ++c) za = fmaf(Wa[c], h[c], za);
    float alive = 1.0f / (1.0f + __expf(-za));

    float r1[12];
    #pragma unroll
    for (int o = 0; o < 12; ++o) {
        float z = br1[o];
        #pragma unroll
        for (int c = 0; c < 12; ++c) z = fmaf(Wr1[o * 13 + c], h[c], z);
        z = fmaf(Wr1[o * 13 + 12], alive, z);
        r1[o] = fmaxf(z, 0.0f);
    }

    float* op = out + (long)b * 16 * Nd + p;
    op[0] = alive;
    #pragma unroll
    for (int j = 0; j < 3; ++j) {
        float z = br2[j];
        #pragma unroll
        for (int o = 0; o < 12; ++o) z = fmaf(Wr2[j * 12 + o], r1[o], z);
        op[(long)(1 + j) * Nd] = (1.0f / (1.0f + __expf(-z))) * alive;
    }
    #pragma unroll
    for (int c = 0; c < 12; ++c) op[(long)(4 + c) * Nd] = h[c];
}

extern "C" void kernel_launch(void* const* d_in, const int* in_sizes, int n_in,
                              void* d_out, int out_size, void* d_ws, size_t ws_size,
                              hipStream_t stream) {
    const float* x   = (const float*)d_in[0];
    // d_in[1] = edge_index — 4-neighbor grid derived analytically, unused
    // d_in[2] = steps (=8) — hardcoded
    const float* Wh  = (const float*)d_in[3];
    const float* bh  = (const float*)d_in[4];
    const float* Wmp = (const float*)d_in[5];
    const float* bmp = (const float*)d_in[6];
    const float* Wa  = (const float*)d_in[7];
    const float* ba  = (const float*)d_in[8];
    const float* Wr1 = (const float*)d_in[9];
    const float* br1 = (const float*)d_in[10];
    const float* Wr2 = (const float*)d_in[11];
    const float* br2 = (const float*)d_in[12];

    float* bufA = (float*)d_out;                       // ping (24MB of 33.5MB)
    float* bufB = (float*)d_ws;                        // pong (24MB)
    float* wtab = (float*)d_out + 12L * Nd * Bd;       // 1740 floats in spare d_out

    nca_prep<<<dim3(7), dim3(256), 0, stream>>>(Wh, bh, Wmp, bmp, wtab);

    dim3 grid(8, 8, 8), block(256);
    const int sb16 = 16 * Nd, sb12 = 12 * Nd;
    nca_step<<<grid, block, 0, stream>>>(x,    sb16, 4 * Nd, bufA, wtab);
    nca_step<<<grid, block, 0, stream>>>(bufA, sb12, 0,      bufB, wtab);
    nca_step<<<grid, block, 0, stream>>>(bufB, sb12, 0,      bufA, wtab);
    nca_step<<<grid, block, 0, stream>>>(bufA, sb12, 0,      bufB, wtab);
    nca_step<<<grid, block, 0, stream>>>(bufB, sb12, 0,      bufA, wtab);
    nca_step<<<grid, block, 0, stream>>>(bufA, sb12, 0,      bufB, wtab);
    nca_step<<<grid, block, 0, stream>>>(bufB, sb12, 0,      bufA, wtab);
    nca_step<<<grid, block, 0, stream>>>(bufA, sb12, 0,      bufB, wtab);
    // final hidden is in bufB (d_ws) -> safe to overwrite all of d_out
    nca_final<<<dim3(Nd / 256, Bd), dim3(256), 0, stream>>>(bufB, (float*)d_out,
                                                            Wa, ba, Wr1, br1, Wr2, br2);
}

// Round 8
// 425.349 us; speedup vs baseline: 1.0582x; 1.0582x over previous
//
#include <hip/hip_runtime.h>
#include <math.h>

#define Wd 256
#define Hd 256
#define Nd (Wd*Hd)
#define Bd 8
#define TS 40              // tile row stride (floats): bank = (8*ty+4*tx)%32 -> 2-way max (free)
#define CS (34*TS)         // per-channel tile size

// wtab layout: [i][o][12]: k=0..8 conv taps (center has +identity), k=9 Wmp[o][i],
// k=10,11 pad. bias[12] (= bh+bmp) at offset 1728. Lives in spare d_out space.
__global__ __launch_bounds__(256) void nca_prep(
    const float* __restrict__ Wh, const float* __restrict__ bh,
    const float* __restrict__ Wmp, const float* __restrict__ bmp,
    float* __restrict__ wtab)
{
    int idx = blockIdx.x * 256 + threadIdx.x;
    if (idx < 1728) {
        int i = idx / 144, rem = idx % 144, o = rem / 12, k = rem % 12;
        float v = 0.0f;
        if (k < 9) {
            v = Wh[(o * 12 + i) * 9 + k];
            if (k == 4 && o == i) v += 1.0f;
        } else if (k == 9) {
            v = Wmp[o * 12 + i];
        }
        wtab[idx] = v;
    } else if (idx < 1740) {
        int o = idx - 1728;
        wtab[idx] = bh[o] + bmp[o];
    }
}

// One NCA step. Three pipes, each on its own counter:
//   taps    -> LDS tile (lgkmcnt/DS, in-order), software-prefetched one i ahead
//   weights -> global via wave-uniform index => s_load / K$ (scalar pipe)
//   math    -> VALU fmacs (480 per i per thread)
// 32x32 tile, 256 threads, 4 px/thread, grid 512 = 2 blocks/CU.
__global__ __launch_bounds__(256, 2) void nca_step(
    const float* __restrict__ src, int sbs, int soff,
    float* __restrict__ dst, const float* __restrict__ wtab)
{
    __shared__ float tile[12 * CS];   // [c][lrow 0..33][stride 40]; lrow0=gy0-1, lcol0=gx0-1

    const int tid = threadIdx.x;
    const int bx = blockIdx.x, by = blockIdx.y, b = blockIdx.z;
    const int x0 = bx * 32, y0 = by * 32;
    const float* sp = src + b * sbs + soff;

    // ---- stage 34x34x12 halo tile; 5 slots/thread, divmod once, reused over c ----
    int jr[5], jc[5]; bool jv[5];
    #pragma unroll
    for (int k = 0; k < 5; ++k) {
        int j = tid + k * 256;
        jv[k] = j < 1156;                 // 34*34
        jr[k] = j / 34; jc[k] = j % 34;
    }
    #pragma unroll 1
    for (int c = 0; c < 12; ++c) {
        const float* cp = sp + c * Nd;
        #pragma unroll
        for (int k = 0; k < 5; ++k) {
            if (jv[k]) {
                int gy = y0 + jr[k] - 1, gx = x0 + jc[k] - 1;
                float v = 0.0f;
                if ((unsigned)gy < 256u && (unsigned)gx < 256u) v = cp[gy * Wd + gx];
                tile[c * CS + jr[k] * TS + jc[k]] = v;
            }
        }
    }
    __syncthreads();

    // ---- compute: 4 px along x per thread ----
    const int tx = tid & 7, ty = tid >> 3;       // ty 0..31
    const int px0 = tx * 4;
    const int gx0 = x0 + px0, gy = y0 + ty;

    float dinv[4];
    #pragma unroll
    for (int p = 0; p < 4; ++p) {
        int gx = gx0 + p;
        int deg = (gx > 0) + (gx < Wd - 1) + (gy > 0) + (gy < Hd - 1);
        dinv[p] = 1.0f / (float)deg;
    }

    const int tbase = ty * TS + px0;

    float acc[4][12];
    #pragma unroll
    for (int o = 0; o < 12; ++o) {
        float bv = wtab[1728 + o];               // uniform -> s_load
        #pragma unroll
        for (int p = 0; p < 4; ++p) acc[p][o] = bv;
    }

    // tap registers for current i, prefetched one i ahead (DS latency hides
    // under the previous iteration's 480-fmac o-loop)
    float4 A0, A1, A2; float2 B0, B1, B2;
    {
        const float* tp = &tile[tbase];          // i = 0
        A0 = *(const float4*)tp;        B0 = *(const float2*)(tp + 4);
        A1 = *(const float4*)(tp + TS); B1 = *(const float2*)(tp + TS + 4);
        A2 = *(const float4*)(tp + 2*TS); B2 = *(const float2*)(tp + 2*TS + 4);
    }

    #pragma unroll 1
    for (int i = 0; i < 12; ++i) {
        // issue next-i tap loads now; consumed next iteration
        float4 nA0, nA1, nA2; float2 nB0, nB1, nB2;
        {
            const int ii = (i < 11) ? i + 1 : 0;
            const float* tp = &tile[ii * CS + tbase];
            nA0 = *(const float4*)tp;        nB0 = *(const float2*)(tp + 4);
            nA1 = *(const float4*)(tp + TS); nB1 = *(const float2*)(tp + TS + 4);
            nA2 = *(const float4*)(tp + 2*TS); nB2 = *(const float2*)(tp + 2*TS + 4);
        }

        float e0[6], e1[6], e2[6];
        e0[0]=A0.x; e0[1]=A0.y; e0[2]=A0.z; e0[3]=A0.w; e0[4]=B0.x; e0[5]=B0.y;
        e1[0]=A1.x; e1[1]=A1.y; e1[2]=A1.z; e1[3]=A1.w; e1[4]=B1.x; e1[5]=B1.y;
        e2[0]=A2.x; e2[1]=A2.y; e2[2]=A2.z; e2[3]=A2.w; e2[4]=B2.x; e2[5]=B2.y;

        float ns[4];
        #pragma unroll
        for (int p = 0; p < 4; ++p)
            ns[p] = (e0[p + 1] + e2[p + 1] + e1[p] + e1[p + 2]) * dinv[p];

        const float4* w4 = (const float4*)(wtab + i * 144);  // uniform -> s_load
        #pragma unroll
        for (int o = 0; o < 12; ++o) {
            float4 wa  = w4[o * 3 + 0];
            float4 wbv = w4[o * 3 + 1];
            float4 wc  = w4[o * 3 + 2];
            #pragma unroll
            for (int p = 0; p < 4; ++p) {
                float a = acc[p][o];
                a = fmaf(wa.x,  e0[p],     a);
                a = fmaf(wa.y,  e0[p + 1], a);
                a = fmaf(wa.z,  e0[p + 2], a);
                a = fmaf(wa.w,  e1[p],     a);
                a = fmaf(wbv.x, e1[p + 1], a);
                a = fmaf(wbv.y, e1[p + 2], a);
                a = fmaf(wbv.z, e2[p],     a);
                a = fmaf(wbv.w, e2[p + 1], a);
                a = fmaf(wc.x,  e2[p + 2], a);
                a = fmaf(wc.y,  ns[p],     a);
                acc[p][o] = a;
            }
        }

        A0 = nA0; B0 = nB0; A1 = nA1; B1 = nB1; A2 = nA2; B2 = nB2;
    }

    // ---- elu + float4 store ----
    float* dp = dst + (long)b * (12L * Nd) + (long)gy * Wd + gx0;
    #pragma unroll
    for (int o = 0; o < 12; ++o) {
        float e[4];
        #pragma unroll
        for (int p = 0; p < 4; ++p) {
            float a = acc[p][o];
            e[p] = a > 0.0f ? a : (__expf(a) - 1.0f);
        }
        *(float4*)&dp[(long)o * Nd] = make_float4(e[0], e[1], e[2], e[3]);
    }
}

// Final: alive/rgb heads + pack output (B,16,H,W)
__global__ __launch_bounds__(256) void nca_final(
    const float* __restrict__ hsrc, float* __restrict__ out,
    const float* __restrict__ Wa, const float* __restrict__ ba,
    const float* __restrict__ Wr1, const float* __restrict__ br1,
    const float* __restrict__ Wr2, const float* __restrict__ br2)
{
    int p = blockIdx.x * 256 + threadIdx.x;
    int b = blockIdx.y;
    const float* hp = hsrc + (long)b * 12 * Nd + p;
    float h[12];
    #pragma unroll
    for (int c = 0; c < 12; ++c) h[c] = hp[(long)c * Nd];

    float za = ba[0];
    #pragma unroll
    for (int c = 0; c < 12; ++c) za = fmaf(Wa[c], h[c], za);
    float alive = 1.0f / (1.0f + __expf(-za));

    float r1[12];
    #pragma unroll
    for (int o = 0; o < 12; ++o) {
        float z = br1[o];
        #pragma unroll
        for (int c = 0; c < 12; ++c) z = fmaf(Wr1[o * 13 + c], h[c], z);
        z = fmaf(Wr1[o * 13 + 12], alive, z);
        r1[o] = fmaxf(z, 0.0f);
    }

    float* op = out + (long)b * 16 * Nd + p;
    op[0] = alive;
    #pragma unroll
    for (int j = 0; j < 3; ++j) {
        float z = br2[j];
        #pragma unroll
        for (int o = 0; o < 12; ++o) z = fmaf(Wr2[j * 12 + o], r1[o], z);
        op[(long)(1 + j) * Nd] = (1.0f / (1.0f + __expf(-z))) * alive;
    }
    #pragma unroll
    for (int c = 0; c < 12; ++c) op[(long)(4 + c) * Nd] = h[c];
}

extern "C" void kernel_launch(void* const* d_in, const int* in_sizes, int n_in,
                              void* d_out, int out_size, void* d_ws, size_t ws_size,
                              hipStream_t stream) {
    const float* x   = (const float*)d_in[0];
    // d_in[1] = edge_index — 4-neighbor grid derived analytically, unused
    // d_in[2] = steps (=8) — hardcoded
    const float* Wh  = (const float*)d_in[3];
    const float* bh  = (const float*)d_in[4];
    const float* Wmp = (const float*)d_in[5];
    const float* bmp = (const float*)d_in[6];
    const float* Wa  = (const float*)d_in[7];
    const float* ba  = (const float*)d_in[8];
    const float* Wr1 = (const float*)d_in[9];
    const float* br1 = (const float*)d_in[10];
    const float* Wr2 = (const float*)d_in[11];
    const float* br2 = (const float*)d_in[12];

    float* bufA = (float*)d_out;                       // ping (24MB of 33.5MB)
    float* bufB = (float*)d_ws;                        // pong (24MB)
    float* wtab = (float*)d_out + 12L * Nd * Bd;       // 1740 floats in spare d_out

    nca_prep<<<dim3(7), dim3(256), 0, stream>>>(Wh, bh, Wmp, bmp, wtab);

    dim3 grid(8, 8, 8), block(256);
    const int sb16 = 16 * Nd, sb12 = 12 * Nd;
    nca_step<<<grid, block, 0, stream>>>(x,    sb16, 4 * Nd, bufA, wtab);
    nca_step<<<grid, block, 0, stream>>>(bufA, sb12, 0,      bufB, wtab);
    nca_step<<<grid, block, 0, stream>>>(bufB, sb12, 0,      bufA, wtab);
    nca_step<<<grid, block, 0, stream>>>(bufA, sb12, 0,      bufB, wtab);
    nca_step<<<grid, block, 0, stream>>>(bufB, sb12, 0,      bufA, wtab);
    nca_step<<<grid, block, 0, stream>>>(bufA, sb12, 0,      bufB, wtab);
    nca_step<<<grid, block, 0, stream>>>(bufB, sb12, 0,      bufA, wtab);
    nca_step<<<grid, block, 0, stream>>>(bufA, sb12, 0,      bufB, wtab);
    // final hidden is in bufB (d_ws) -> safe to overwrite all of d_out
    nca_final<<<dim3(Nd / 256, Bd), dim3(256), 0, stream>>>(bufB, (float*)d_out,
                                                            Wa, ba, Wr1, br1, Wr2, br2);
}